// Round 8
// baseline (446.886 us; speedup 1.0000x reference)
//
#include <hip/hip_runtime.h>
#include <hip/hip_bf16.h>
#include <math.h>

#define NN 50000
#define EE 800000
#define CC 192

typedef __attribute__((ext_vector_type(4))) float f32x4;
typedef __attribute__((ext_vector_type(8))) short bfx8;
typedef __attribute__((ext_vector_type(8))) unsigned short u16x8;

static __device__ __forceinline__ unsigned short f2bf(float f) {
    return __builtin_bit_cast(unsigned short, __float2bfloat16(f));
}
static __device__ __forceinline__ float b2f(unsigned short u) {
    unsigned v = ((unsigned)u) << 16;
    return __builtin_bit_cast(float, v);
}

// ---- A-staging row converter ----
// MODE: 0 = plain bf16, 1 = fp32->bf16, 2 = affine(A*v+B)->bf16, 3 = affine+gelu->bf16
template <int MODE>
static __device__ __forceinline__ bfx8 stage_row(const void* Ap, size_t off, int kc,
                                                 const float* __restrict__ Av,
                                                 const float* __restrict__ Bv)
{
    if constexpr (MODE == 1) {
        const float* A = (const float*)Ap;
        float4 u0 = *(const float4*)&A[off], u1 = *(const float4*)&A[off + 4];
        return bfx8{(short)f2bf(u0.x), (short)f2bf(u0.y), (short)f2bf(u0.z), (short)f2bf(u0.w),
                    (short)f2bf(u1.x), (short)f2bf(u1.y), (short)f2bf(u1.z), (short)f2bf(u1.w)};
    } else {
        u16x8 ra = *(const u16x8*)((const unsigned short*)Ap + off);
        if constexpr (MODE == 0) {
            return __builtin_bit_cast(bfx8, ra);
        } else {
            float pa[8], pb[8];
            *(float4*)&pa[0] = *(const float4*)&Av[kc];
            *(float4*)&pa[4] = *(const float4*)&Av[kc + 4];
            *(float4*)&pb[0] = *(const float4*)&Bv[kc];
            *(float4*)&pb[4] = *(const float4*)&Bv[kc + 4];
            bfx8 o;
#pragma unroll
            for (int j = 0; j < 8; ++j) {
                float t = pa[j] * b2f(ra[j]) + pb[j];
                if constexpr (MODE == 3)
                    t = 0.5f * t * (1.f + erff(t * 0.70710678118654752f));
                o[j] = (short)f2bf(t);
            }
            return o;
        }
    }
}

// ============ bf16 MFMA GEMM: out = bf16(f(A1)@W1^T (+ f(A2)@W2^T) + bias) ============
// 128x128 tile, BK=32, 4 waves 2x2, 16x16x32 MFMA, XCD-bijective swizzle,
// fused BN stats, LDS-staged coalesced epilogue. A-modes per stage_row.
#define BM 128
#define BKD 32
#define SA 40
#define CT 136

template <int A1M, int A2M, bool STATS>
__global__ __launch_bounds__(256) void gemm_mfma(
    const void* __restrict__ A1v, const unsigned short* __restrict__ W1,
    const void* __restrict__ A2v, const unsigned short* __restrict__ W2,
    const float* __restrict__ bias,
    const float* __restrict__ Av, const float* __restrict__ Bv,
    unsigned short* __restrict__ outb,
    float* __restrict__ gsum, float* __restrict__ gsq,
    int Nrows, int K, int M)
{
    __shared__ short lds[2][2][BM * SA];   // reused as C tile
    __shared__ float s_sum[BM], s_sq[BM];
    const int tid  = threadIdx.x;
    const int lane = tid & 63;
    const int wave = tid >> 6;
    const int wm = wave >> 1, wn = wave & 1;

    // bijective XCD swizzle (8 XCDs)
    const int gx = gridDim.x;
    const int nwg = gx * gridDim.y;
    const int linear = blockIdx.y * gx + blockIdx.x;
    const int q = nwg >> 3, r = nwg & 7;
    const int xcd = linear & 7, idx = linear >> 3;
    const int swz = (xcd < r ? xcd * (q + 1) : r * (q + 1) + (xcd - r) * q) + idx;
    const int row0 = (swz / gx) * BM;
    const int col0 = (swz % gx) * BM;

    const int nk = K / BKD;
    const int ntot = (A2M >= 0) ? 2 * nk : nk;

    const int ar = tid >> 2;
    const int ko = (tid & 3) * 8;

    f32x4 acc[4][4];
#pragma unroll
    for (int i = 0; i < 4; ++i)
#pragma unroll
        for (int j = 0; j < 4; ++j) acc[i][j] = f32x4{0.f, 0.f, 0.f, 0.f};

    const int r0c = min(row0 + ar, Nrows - 1);
    const int r1c = min(row0 + ar + 64, Nrows - 1);
    const int c0c = min(col0 + ar, M - 1);
    const int c1c = min(col0 + ar + 64, M - 1);

    auto load_step = [&](int t, bfx8& a0, bfx8& a1, bfx8& b0, bfx8& b1) {
        const int p = (A2M >= 0 && t >= nk) ? 1 : 0;
        const int k0 = (t - p * nk) * BKD;
        const int kc = k0 + ko;
        const unsigned short* W = p ? W2 : W1;
        if (!p) {
            a0 = stage_row<A1M>(A1v, (size_t)r0c * K + kc, kc, Av, Bv);
            a1 = stage_row<A1M>(A1v, (size_t)r1c * K + kc, kc, Av, Bv);
        } else {
            constexpr int M2 = (A2M < 0) ? 0 : A2M;
            a0 = stage_row<M2>(A2v, (size_t)r0c * K + kc, kc, Av, Bv);
            a1 = stage_row<M2>(A2v, (size_t)r1c * K + kc, kc, Av, Bv);
        }
        b0 = *(const bfx8*)&W[(size_t)c0c * K + kc];
        b1 = *(const bfx8*)&W[(size_t)c1c * K + kc];
    };
    auto write_step = [&](int buf, bfx8 a0, bfx8 a1, bfx8 b0, bfx8 b1) {
        *(bfx8*)&lds[buf][0][ar * SA + ko] = a0;
        *(bfx8*)&lds[buf][0][(ar + 64) * SA + ko] = a1;
        *(bfx8*)&lds[buf][1][ar * SA + ko] = b0;
        *(bfx8*)&lds[buf][1][(ar + 64) * SA + ko] = b1;
    };
    auto compute = [&](int buf) {
        const short* Al = lds[buf][0];
        const short* Bl = lds[buf][1];
        bfx8 af[4], bfr[4];
        const int rbase = wm * 64 + (lane & 15);
        const int cbase = wn * 64 + (lane & 15);
        const int kroff = (lane >> 4) * 8;
#pragma unroll
        for (int i = 0; i < 4; ++i) af[i]  = *(const bfx8*)&Al[(rbase + i * 16) * SA + kroff];
#pragma unroll
        for (int j = 0; j < 4; ++j) bfr[j] = *(const bfx8*)&Bl[(cbase + j * 16) * SA + kroff];
#pragma unroll
        for (int i = 0; i < 4; ++i)
#pragma unroll
            for (int j = 0; j < 4; ++j)
                acc[i][j] = __builtin_amdgcn_mfma_f32_16x16x32_bf16(af[i], bfr[j], acc[i][j], 0, 0, 0);
    };

    bfx8 a0, a1, b0, b1;
    load_step(0, a0, a1, b0, b1);
    write_step(0, a0, a1, b0, b1);
    for (int t = 0; t < ntot; ++t) {
        const bool more = (t + 1 < ntot);
        if (more) load_step(t + 1, a0, a1, b0, b1);
        __syncthreads();
        compute(t & 1);
        if (more) write_step((t + 1) & 1, a0, a1, b0, b1);
    }

    // ---- epilogue: register stats + LDS-staged coalesced store ----
    if (STATS) {
        if (tid < BM) { s_sum[tid] = 0.f; s_sq[tid] = 0.f; }
    }
    __syncthreads();
    short* ctile = &lds[0][0][0];  // [BM][CT]
#pragma unroll
    for (int j = 0; j < 4; ++j) {
        const int cl = wn * 64 + j * 16 + (lane & 15);
        const int c = col0 + cl;
        const float bv = (c < M) ? bias[c] : 0.f;
        float cs = 0.f, cq = 0.f;
#pragma unroll
        for (int i = 0; i < 4; ++i) {
            const int rl = wm * 64 + i * 16 + (lane >> 4) * 4;
#pragma unroll
            for (int r2 = 0; r2 < 4; ++r2) {
                const float val = acc[i][j][r2] + bv;
                ctile[(rl + r2) * CT + cl] = (short)f2bf(val);
                if (STATS) {
                    if (c < M && row0 + rl + r2 < Nrows) { cs += val; cq += val * val; }
                }
            }
        }
        if (STATS && c < M) {
            atomicAdd(&s_sum[cl], cs);
            atomicAdd(&s_sq[cl], cq);
        }
    }
    __syncthreads();
    {
        const int rl0 = tid >> 4;
        const int co  = (tid & 15) * 8;
        const int cg  = col0 + co;
        if (cg < M) {
#pragma unroll
            for (int it = 0; it < 8; ++it) {
                const int rl = rl0 + it * 16;
                const int rg = row0 + rl;
                if (rg < Nrows) {
                    u16x8 v = *(const u16x8*)&ctile[rl * CT + co];
                    *(u16x8*)&outb[(size_t)rg * M + cg] = v;
                }
            }
        }
    }
    if (STATS) {
        if (tid < BM) {
            const int c = col0 + tid;
            if (c < M) {
                atomicAdd(&gsum[c], s_sum[tid]);
                atomicAdd(&gsq[c], s_sq[tid]);
            }
        }
    }
}

// ============ weight conversion fp32 -> bf16 arena ============
#define W_G1 0
#define W_REL 49152
#define W_ROOT 180224
#define W_G2 311296
#define W_F1 409600
#define W_F2 507904
#define W_TOT 606208

__global__ __launch_bounds__(256) void convert_weights(
    const float* __restrict__ w0, const float* __restrict__ w1, const float* __restrict__ w2,
    const float* __restrict__ w3, const float* __restrict__ w4, const float* __restrict__ w5,
    unsigned short* __restrict__ out)
{
    int i = blockIdx.x * 256 + threadIdx.x;
    if (i >= W_TOT) return;
    const float* src; int off;
    if      (i < W_REL)  { src = w0; off = W_G1; }
    else if (i < W_ROOT) { src = w1; off = W_REL; }
    else if (i < W_G2)   { src = w2; off = W_ROOT; }
    else if (i < W_F1)   { src = w3; off = W_G2; }
    else if (i < W_F2)   { src = w4; off = W_F1; }
    else                 { src = w5; off = W_F2; }
    out[i] = f2bf(src[i - off]);
}

// ============ BN finalize: mu/rs + affine (Av,Bv); self-zeroes sums ============
__global__ __launch_bounds__(256) void bn_finalize(
    float* __restrict__ sum, float* __restrict__ sumsq,
    const float* __restrict__ g, const float* __restrict__ b,
    float* __restrict__ mu, float* __restrict__ rs,
    float* __restrict__ Av, float* __restrict__ Bv, int M, float invN)
{
    int i = blockIdx.x * 256 + threadIdx.x;   // grid 2 -> 512 threads
    if (i < 512) {
        if (i < M) {
            float m = sum[i] * invN;
            float v = sumsq[i] * invN - m * m;
            float r = rsqrtf(v + 1e-5f);
            mu[i] = m; rs[i] = r;
            Av[i] = g[i] * r;
            Bv[i] = b[i] - g[i] * m * r;
        }
        sum[i] = 0.f; sumsq[i] = 0.f;
    }
}

// ============ BN apply (channel-stationary) ============
// MODE: 2 = +res(fp32)->bf16, 3 = +res(bf16)->fp32
template <int MODE>
__global__ __launch_bounds__(256) void bn_apply2(
    const unsigned short* __restrict__ pre, const void* __restrict__ resv,
    void* __restrict__ outv, int total8, int M8,
    const float* __restrict__ g, const float* __restrict__ b,
    const float* __restrict__ mu, const float* __restrict__ rs)
{
    const int i0 = blockIdx.x * 256 + threadIdx.x;
    if (i0 >= total8) return;
    const int c = (i0 % M8) * 8;
    float gg[8], bb[8], mm[8], rr[8];
    *(float4*)&gg[0] = *(const float4*)&g[c];   *(float4*)&gg[4] = *(const float4*)&g[c + 4];
    *(float4*)&bb[0] = *(const float4*)&b[c];   *(float4*)&bb[4] = *(const float4*)&b[c + 4];
    *(float4*)&mm[0] = *(const float4*)&mu[c];  *(float4*)&mm[4] = *(const float4*)&mu[c + 4];
    *(float4*)&rr[0] = *(const float4*)&rs[c];  *(float4*)&rr[4] = *(const float4*)&rs[c + 4];
    const int stride = gridDim.x * 256;
    for (int i = i0; i < total8; i += stride) {
        u16x8 v = *(const u16x8*)&pre[(size_t)i * 8];
        float t[8];
#pragma unroll
        for (int k = 0; k < 8; ++k)
            t[k] = gg[k] * (b2f(v[k]) - mm[k]) * rr[k] + bb[k];
        if (MODE == 2) {
            const float* res = (const float*)resv;
            float4 x0 = *(const float4*)&res[(size_t)i * 8];
            float4 x1 = *(const float4*)&res[(size_t)i * 8 + 4];
            t[0] += x0.x; t[1] += x0.y; t[2] += x0.z; t[3] += x0.w;
            t[4] += x1.x; t[5] += x1.y; t[6] += x1.z; t[7] += x1.w;
            unsigned short* ob = (unsigned short*)outv;
            u16x8 o;
#pragma unroll
            for (int k = 0; k < 8; ++k) o[k] = f2bf(t[k]);
            *(u16x8*)&ob[(size_t)i * 8] = o;
        } else {
            const unsigned short* resb = (const unsigned short*)resv;
            u16x8 xb = *(const u16x8*)&resb[(size_t)i * 8];
#pragma unroll
            for (int k = 0; k < 8; ++k) t[k] += b2f(xb[k]);
            float* outp = (float*)outv;
            *(float4*)&outp[(size_t)i * 8]     = make_float4(t[0], t[1], t[2], t[3]);
            *(float4*)&outp[(size_t)i * 8 + 4] = make_float4(t[4], t[5], t[6], t[7]);
        }
    }
}

// ============ CSR build ============
__global__ __launch_bounds__(256) void hist_count(
    const int* __restrict__ dst, int* __restrict__ cnt, int E)
{
    int e = blockIdx.x * blockDim.x + threadIdx.x;
    if (e < E) atomicAdd(&cnt[dst[e]], 1);
}

__global__ __launch_bounds__(256) void scan_block_sums(
    const int* __restrict__ cnt, int* __restrict__ partials, int n)
{
    __shared__ int sdata[256];
    int i = blockIdx.x * 256 + threadIdx.x;
    sdata[threadIdx.x] = (i < n) ? cnt[i] : 0;
    __syncthreads();
    for (int s = 128; s > 0; s >>= 1) {
        if (threadIdx.x < s) sdata[threadIdx.x] += sdata[threadIdx.x + s];
        __syncthreads();
    }
    if (threadIdx.x == 0) partials[blockIdx.x] = sdata[0];
}

__global__ __launch_bounds__(256) void scan_partials(
    int* __restrict__ partials, int nb, int* __restrict__ row_start, int n, int E)
{
    __shared__ int sdata[256];
    const int t = threadIdx.x;
    const int v = (t < nb) ? partials[t] : 0;
    sdata[t] = v;
    __syncthreads();
    for (int s = 1; s < 256; s <<= 1) {
        int u = (t >= s) ? sdata[t - s] : 0;
        __syncthreads();
        sdata[t] += u;
        __syncthreads();
    }
    if (t < nb) partials[t] = sdata[t] - v;
    if (t == 0) row_start[n] = E;
}

__global__ __launch_bounds__(256) void scan_final(
    const int* __restrict__ cnt, const int* __restrict__ partials,
    int* __restrict__ row_start, int n)
{
    __shared__ int sdata[256];
    int i = blockIdx.x * 256 + threadIdx.x;
    int v = (i < n) ? cnt[i] : 0;
    sdata[threadIdx.x] = v;
    __syncthreads();
    for (int s = 1; s < 256; s <<= 1) {
        int t = (threadIdx.x >= s) ? sdata[threadIdx.x - s] : 0;
        __syncthreads();
        sdata[threadIdx.x] += t;
        __syncthreads();
    }
    if (i < n) row_start[i] = partials[blockIdx.x] + sdata[threadIdx.x] - v;
}

__global__ __launch_bounds__(256) void csr_fill(
    const int* __restrict__ src, const int* __restrict__ dst,
    const int* __restrict__ row_start, int* __restrict__ cursor,
    int* __restrict__ srcs_sorted, int E)
{
    int e = blockIdx.x * blockDim.x + threadIdx.x;
    if (e < E) {
        int d = dst[e];
        int pos = row_start[d] + atomicAdd(&cursor[d], 1);
        srcs_sorted[pos] = src[e];
    }
}

// ============ gather-sum with fused BN affine ============
// AGG_bn[n] = Av * (sum of raw Pre rows) + deg * Bv   (exact fold of BN into segsum)
__global__ __launch_bounds__(256) void gather_sum(
    const int* __restrict__ row_start, const int* __restrict__ srcs,
    const unsigned short* __restrict__ T, unsigned short* __restrict__ AGG,
    const float* __restrict__ Av, const float* __restrict__ Bv, int Nn)
{
    int n = blockIdx.x * 4 + (threadIdx.x >> 6);
    if (n >= Nn) return;
    const int lane = threadIdx.x & 63;
    const int half = lane >> 5;
    const int c0 = (lane & 31) * 8;
    const int e0 = row_start[n], e1 = row_start[n + 1];
    float a[8];
#pragma unroll
    for (int k = 0; k < 8; ++k) a[k] = 0.f;

    int e = e0 + half;
    for (; e + 6 < e1; e += 8) {
        int s0 = srcs[e], s1 = srcs[e + 2], s2 = srcs[e + 4], s3 = srcs[e + 6];
        u16x8 v0 = *(const u16x8*)&T[(size_t)s0 * 256 + c0];
        u16x8 v1 = *(const u16x8*)&T[(size_t)s1 * 256 + c0];
        u16x8 v2 = *(const u16x8*)&T[(size_t)s2 * 256 + c0];
        u16x8 v3 = *(const u16x8*)&T[(size_t)s3 * 256 + c0];
#pragma unroll
        for (int k = 0; k < 8; ++k)
            a[k] += (b2f(v0[k]) + b2f(v1[k])) + (b2f(v2[k]) + b2f(v3[k]));
    }
    for (; e < e1; e += 2) {
        int s = srcs[e];
        u16x8 v = *(const u16x8*)&T[(size_t)s * 256 + c0];
#pragma unroll
        for (int k = 0; k < 8; ++k) a[k] += b2f(v[k]);
    }
#pragma unroll
    for (int k = 0; k < 8; ++k) a[k] += __shfl_xor(a[k], 32);
    if (half == 0) {
        const float deg = (float)(e1 - e0);
        float pa[8], pb[8];
        *(float4*)&pa[0] = *(const float4*)&Av[c0];
        *(float4*)&pa[4] = *(const float4*)&Av[c0 + 4];
        *(float4*)&pb[0] = *(const float4*)&Bv[c0];
        *(float4*)&pb[4] = *(const float4*)&Bv[c0 + 4];
        u16x8 o;
#pragma unroll
        for (int k = 0; k < 8; ++k) o[k] = f2bf(pa[k] * a[k] + deg * pb[k]);
        *(u16x8*)&AGG[(size_t)n * 256 + c0] = o;
    }
}

// =====================================================================
extern "C" void kernel_launch(void* const* d_in, const int* in_sizes, int n_in,
                              void* d_out, int out_size, void* d_ws, size_t ws_size,
                              hipStream_t stream)
{
    const float* x        = (const float*)d_in[0];
    const int*   ei       = (const int*)d_in[1];
    const float* w_g1     = (const float*)d_in[2];
    const float* b_g1     = (const float*)d_in[3];
    const float* g1_gamma = (const float*)d_in[4];
    const float* g1_beta  = (const float*)d_in[5];
    const float* w_rel    = (const float*)d_in[6];
    const float* b_rel    = (const float*)d_in[7];
    const float* w_root   = (const float*)d_in[8];
    const float* w_g2     = (const float*)d_in[9];
    const float* b_g2     = (const float*)d_in[10];
    const float* g2_gamma = (const float*)d_in[11];
    const float* g2_beta  = (const float*)d_in[12];
    const float* w_f1     = (const float*)d_in[13];
    const float* b_f1     = (const float*)d_in[14];
    const float* f1_gamma = (const float*)d_in[15];
    const float* f1_beta  = (const float*)d_in[16];
    const float* w_f2     = (const float*)d_in[17];
    const float* b_f2     = (const float*)d_in[18];
    const float* f2_gamma = (const float*)d_in[19];
    const float* f2_beta  = (const float*)d_in[20];

    const int* src = ei;
    const int* dst = ei + EE;

    // workspace layout
    char* p = (char*)d_ws;
    unsigned short* Pre = (unsigned short*)p;   p += (size_t)NN * 512 * 2;  // fc1 pre-BN / ffn hidden pre-BN
    unsigned short* R2 = (unsigned short*)p;    p += (size_t)NN * 512 * 2;  // Hb, then G12 output
    unsigned short* R3 = (unsigned short*)p;    p += (size_t)NN * 256 * 2;  // CSR scratch, then X2b
    unsigned short* R4 = (unsigned short*)p;    p += (size_t)NN * 256 * 2;  // AGGb
    unsigned short* Wb = (unsigned short*)p;    p += 2 * 1024 * 1024;       // bf16 weights
    float* sum   = (float*)p;
    float* sumsq = sum + 512;
    float* mu    = sum + 1024;
    float* rs    = sum + 1536;
    float* Avec  = sum + 2048;
    float* Bvec  = sum + 2560;

    unsigned short* AGGb = R4;
    unsigned short* Hb   = R2;
    unsigned short* X2b  = R3;
    unsigned short* P12  = R2;   // G12 pre-BN output (Hb dead after GEMM6)

    // CSR scratch in R3 (dead once gather completes; X2b written later)
    int* row_start   = (int*)R3;             // NN+1
    int* cnt         = row_start + NN + 16;
    int* cursor      = cnt + NN;
    int* partials    = cursor + NN;
    int* srcs_sorted = partials + 256;       // EE

    float* out = (float*)d_out;
    const float invN = 1.f / (float)NN;
    dim3 blk(256);
    const int GY = (NN + 127) / 128;         // 391
    const int NB_SCAN = (NN + 255) / 256;    // 196
    const int BN_GRID = 1536;                // 393216 ≡ 0 mod 24

    auto finalize = [&](int M, const float* g, const float* b) {
        hipLaunchKernelGGL(bn_finalize, dim3(2), dim3(256), 0, stream,
                           sum, sumsq, g, b, mu, rs, Avec, Bvec, M, invN);
    };

    // 0. weights -> bf16 arena; zero stats once (finalizes self-zero afterwards)
    hipLaunchKernelGGL(convert_weights, dim3((W_TOT + 255) / 256), blk, 0, stream,
                       w_g1, w_rel, w_root, w_g2, w_f1, w_f2, Wb);
    hipMemsetAsync(sum, 0, 1024 * sizeof(float), stream);

    // ---- Grapher ----
    // 1. Pre = x @ w_g1^T + b_g1   [N,256]  + stats
    hipLaunchKernelGGL((gemm_mfma<1, -1, true>), dim3(2, GY), blk, 0, stream,
                       (const void*)x, Wb + W_G1, nullptr, nullptr, b_g1, nullptr, nullptr,
                       Pre, sum, sumsq, NN, CC, 256);
    finalize(256, g1_gamma, g1_beta);
    // 2. CSR build + gather with fused BN affine (AGGb = Av*segsum(Pre[src]) + deg*Bv)
    hipMemsetAsync(cnt, 0, 2 * NN * sizeof(int), stream);
    hipLaunchKernelGGL(hist_count, dim3((EE + 255) / 256), blk, 0, stream, dst, cnt, EE);
    hipLaunchKernelGGL(scan_block_sums, dim3(NB_SCAN), blk, 0, stream, cnt, partials, NN);
    hipLaunchKernelGGL(scan_partials, dim3(1), dim3(256), 0, stream, partials, NB_SCAN,
                       row_start, NN, EE);
    hipLaunchKernelGGL(scan_final, dim3(NB_SCAN), blk, 0, stream, cnt, partials, row_start, NN);
    hipLaunchKernelGGL(csr_fill, dim3((EE + 255) / 256), blk, 0, stream, src, dst,
                       row_start, cursor, srcs_sorted, EE);
    hipLaunchKernelGGL(gather_sum, dim3((NN + 3) / 4), blk, 0, stream,
                       row_start, srcs_sorted, Pre, AGGb, Avec, Bvec, NN);
    // 3. Hb = bf16(AGGb @ w_rel^T + b_rel + affine(Pre) @ w_root^T)   [N,512]
    hipLaunchKernelGGL((gemm_mfma<0, 2, false>), dim3(4, GY), blk, 0, stream,
                       (const void*)AGGb, Wb + W_REL, (const void*)Pre, Wb + W_ROOT,
                       b_rel, Avec, Bvec, Hb, nullptr, nullptr, NN, 256, 512);
    // 4. Pre = Hb @ w_g2^T + b_g2   [N,192]  + stats
    hipLaunchKernelGGL((gemm_mfma<0, -1, true>), dim3(2, GY), blk, 0, stream,
                       (const void*)Hb, Wb + W_G2, nullptr, nullptr, b_g2, nullptr, nullptr,
                       Pre, sum, sumsq, NN, 512, CC);
    finalize(CC, g2_gamma, g2_beta);
    // 5. X2b = bf16(BN(Pre) + x)
    hipLaunchKernelGGL((bn_apply2<2>), dim3(BN_GRID), blk, 0, stream, Pre, (const void*)x,
                       (void*)X2b, NN * 24, 24, g2_gamma, g2_beta, mu, rs);
    // ---- FFN ----
    // 6. Pre = X2b @ w_f1^T + b_f1   [N,512]  + stats
    hipLaunchKernelGGL((gemm_mfma<0, -1, true>), dim3(4, GY), blk, 0, stream,
                       (const void*)X2b, Wb + W_F1, nullptr, nullptr, b_f1, nullptr, nullptr,
                       Pre, sum, sumsq, NN, CC, 512);
    finalize(512, f1_gamma, f1_beta);
    // 7. P12 = gelu(affine(Pre)) @ w_f2^T + b_f2   [N,192]  + stats  (BN+gelu fused in staging)
    hipLaunchKernelGGL((gemm_mfma<3, -1, true>), dim3(2, GY), blk, 0, stream,
                       (const void*)Pre, Wb + W_F2, nullptr, nullptr, b_f2, Avec, Bvec,
                       P12, sum, sumsq, NN, 512, CC);
    finalize(CC, f2_gamma, f2_beta);
    // 8. out = BN(P12) + X2b
    hipLaunchKernelGGL((bn_apply2<3>), dim3(BN_GRID), blk, 0, stream, P12, (const void*)X2b,
                       (void*)out, NN * 24, 24, f2_gamma, f2_beta, mu, rs);

    (void)in_sizes; (void)n_in; (void)out_size; (void)ws_size;
}

// Round 9
// 421.325 us; speedup vs baseline: 1.0607x; 1.0607x over previous
//
#include <hip/hip_runtime.h>
#include <hip/hip_bf16.h>
#include <math.h>

#define NN 50000
#define EE 800000
#define CC 192

typedef __attribute__((ext_vector_type(4))) float f32x4;
typedef __attribute__((ext_vector_type(8))) short bfx8;
typedef __attribute__((ext_vector_type(8))) unsigned short u16x8;

static __device__ __forceinline__ unsigned short f2bf(float f) {
    return __builtin_bit_cast(unsigned short, __float2bfloat16(f));
}
static __device__ __forceinline__ float b2f(unsigned short u) {
    unsigned v = ((unsigned)u) << 16;
    return __builtin_bit_cast(float, v);
}

// ---- A-staging row converter ----
// MODE: 0 = plain bf16, 1 = fp32->bf16, 2 = affine(A*v+B)->bf16  (no transcendentals here!)
template <int MODE>
static __device__ __forceinline__ bfx8 stage_row(const void* Ap, size_t off, int kc,
                                                 const float* __restrict__ Av,
                                                 const float* __restrict__ Bv)
{
    if constexpr (MODE == 1) {
        const float* A = (const float*)Ap;
        float4 u0 = *(const float4*)&A[off], u1 = *(const float4*)&A[off + 4];
        return bfx8{(short)f2bf(u0.x), (short)f2bf(u0.y), (short)f2bf(u0.z), (short)f2bf(u0.w),
                    (short)f2bf(u1.x), (short)f2bf(u1.y), (short)f2bf(u1.z), (short)f2bf(u1.w)};
    } else {
        u16x8 ra = *(const u16x8*)((const unsigned short*)Ap + off);
        if constexpr (MODE == 0) {
            return __builtin_bit_cast(bfx8, ra);
        } else {
            float pa[8], pb[8];
            *(float4*)&pa[0] = *(const float4*)&Av[kc];
            *(float4*)&pa[4] = *(const float4*)&Av[kc + 4];
            *(float4*)&pb[0] = *(const float4*)&Bv[kc];
            *(float4*)&pb[4] = *(const float4*)&Bv[kc + 4];
            bfx8 o;
#pragma unroll
            for (int j = 0; j < 8; ++j) {
                float t = pa[j] * b2f(ra[j]) + pb[j];
                o[j] = (short)f2bf(t);
            }
            return o;
        }
    }
}

// ============ bf16 MFMA GEMM: out = bf16(f(A1)@W1^T (+ f(A2)@W2^T) + bias) ============
// 128x128 tile, BK=32, 4 waves 2x2, 16x16x32 MFMA, XCD-bijective swizzle,
// fused BN stats, LDS-staged coalesced epilogue. A-modes per stage_row.
#define BM 128
#define BKD 32
#define SA 40
#define CT 136

template <int A1M, int A2M, bool STATS>
__global__ __launch_bounds__(256) void gemm_mfma(
    const void* __restrict__ A1v, const unsigned short* __restrict__ W1,
    const void* __restrict__ A2v, const unsigned short* __restrict__ W2,
    const float* __restrict__ bias,
    const float* __restrict__ Av, const float* __restrict__ Bv,
    unsigned short* __restrict__ outb,
    float* __restrict__ gsum, float* __restrict__ gsq,
    int Nrows, int K, int M)
{
    __shared__ short lds[2][2][BM * SA];   // reused as C tile
    __shared__ float s_sum[BM], s_sq[BM];
    const int tid  = threadIdx.x;
    const int lane = tid & 63;
    const int wave = tid >> 6;
    const int wm = wave >> 1, wn = wave & 1;

    // bijective XCD swizzle (8 XCDs)
    const int gx = gridDim.x;
    const int nwg = gx * gridDim.y;
    const int linear = blockIdx.y * gx + blockIdx.x;
    const int q = nwg >> 3, r = nwg & 7;
    const int xcd = linear & 7, idx = linear >> 3;
    const int swz = (xcd < r ? xcd * (q + 1) : r * (q + 1) + (xcd - r) * q) + idx;
    const int row0 = (swz / gx) * BM;
    const int col0 = (swz % gx) * BM;

    const int nk = K / BKD;
    const int ntot = (A2M >= 0) ? 2 * nk : nk;

    const int ar = tid >> 2;
    const int ko = (tid & 3) * 8;

    f32x4 acc[4][4];
#pragma unroll
    for (int i = 0; i < 4; ++i)
#pragma unroll
        for (int j = 0; j < 4; ++j) acc[i][j] = f32x4{0.f, 0.f, 0.f, 0.f};

    const int r0c = min(row0 + ar, Nrows - 1);
    const int r1c = min(row0 + ar + 64, Nrows - 1);
    const int c0c = min(col0 + ar, M - 1);
    const int c1c = min(col0 + ar + 64, M - 1);

    auto load_step = [&](int t, bfx8& a0, bfx8& a1, bfx8& b0, bfx8& b1) {
        const int p = (A2M >= 0 && t >= nk) ? 1 : 0;
        const int k0 = (t - p * nk) * BKD;
        const int kc = k0 + ko;
        const unsigned short* W = p ? W2 : W1;
        if (!p) {
            a0 = stage_row<A1M>(A1v, (size_t)r0c * K + kc, kc, Av, Bv);
            a1 = stage_row<A1M>(A1v, (size_t)r1c * K + kc, kc, Av, Bv);
        } else {
            constexpr int M2 = (A2M < 0) ? 0 : A2M;
            a0 = stage_row<M2>(A2v, (size_t)r0c * K + kc, kc, Av, Bv);
            a1 = stage_row<M2>(A2v, (size_t)r1c * K + kc, kc, Av, Bv);
        }
        b0 = *(const bfx8*)&W[(size_t)c0c * K + kc];
        b1 = *(const bfx8*)&W[(size_t)c1c * K + kc];
    };
    auto write_step = [&](int buf, bfx8 a0, bfx8 a1, bfx8 b0, bfx8 b1) {
        *(bfx8*)&lds[buf][0][ar * SA + ko] = a0;
        *(bfx8*)&lds[buf][0][(ar + 64) * SA + ko] = a1;
        *(bfx8*)&lds[buf][1][ar * SA + ko] = b0;
        *(bfx8*)&lds[buf][1][(ar + 64) * SA + ko] = b1;
    };
    auto compute = [&](int buf) {
        const short* Al = lds[buf][0];
        const short* Bl = lds[buf][1];
        bfx8 af[4], bfr[4];
        const int rbase = wm * 64 + (lane & 15);
        const int cbase = wn * 64 + (lane & 15);
        const int kroff = (lane >> 4) * 8;
#pragma unroll
        for (int i = 0; i < 4; ++i) af[i]  = *(const bfx8*)&Al[(rbase + i * 16) * SA + kroff];
#pragma unroll
        for (int j = 0; j < 4; ++j) bfr[j] = *(const bfx8*)&Bl[(cbase + j * 16) * SA + kroff];
#pragma unroll
        for (int i = 0; i < 4; ++i)
#pragma unroll
            for (int j = 0; j < 4; ++j)
                acc[i][j] = __builtin_amdgcn_mfma_f32_16x16x32_bf16(af[i], bfr[j], acc[i][j], 0, 0, 0);
    };

    bfx8 a0, a1, b0, b1;
    load_step(0, a0, a1, b0, b1);
    write_step(0, a0, a1, b0, b1);
    for (int t = 0; t < ntot; ++t) {
        const bool more = (t + 1 < ntot);
        if (more) load_step(t + 1, a0, a1, b0, b1);
        __syncthreads();
        compute(t & 1);
        if (more) write_step((t + 1) & 1, a0, a1, b0, b1);
    }

    // ---- epilogue: register stats + LDS-staged coalesced store ----
    if (STATS) {
        if (tid < BM) { s_sum[tid] = 0.f; s_sq[tid] = 0.f; }
    }
    __syncthreads();
    short* ctile = &lds[0][0][0];  // [BM][CT]
#pragma unroll
    for (int j = 0; j < 4; ++j) {
        const int cl = wn * 64 + j * 16 + (lane & 15);
        const int c = col0 + cl;
        const float bv = (c < M) ? bias[c] : 0.f;
        float cs = 0.f, cq = 0.f;
#pragma unroll
        for (int i = 0; i < 4; ++i) {
            const int rl = wm * 64 + i * 16 + (lane >> 4) * 4;
#pragma unroll
            for (int r2 = 0; r2 < 4; ++r2) {
                const float val = acc[i][j][r2] + bv;
                ctile[(rl + r2) * CT + cl] = (short)f2bf(val);
                if (STATS) {
                    if (c < M && row0 + rl + r2 < Nrows) { cs += val; cq += val * val; }
                }
            }
        }
        if (STATS && c < M) {
            atomicAdd(&s_sum[cl], cs);
            atomicAdd(&s_sq[cl], cq);
        }
    }
    __syncthreads();
    {
        const int rl0 = tid >> 4;
        const int co  = (tid & 15) * 8;
        const int cg  = col0 + co;
        if (cg < M) {
#pragma unroll
            for (int it = 0; it < 8; ++it) {
                const int rl = rl0 + it * 16;
                const int rg = row0 + rl;
                if (rg < Nrows) {
                    u16x8 v = *(const u16x8*)&ctile[rl * CT + co];
                    *(u16x8*)&outb[(size_t)rg * M + cg] = v;
                }
            }
        }
    }
    if (STATS) {
        if (tid < BM) {
            const int c = col0 + tid;
            if (c < M) {
                atomicAdd(&gsum[c], s_sum[tid]);
                atomicAdd(&gsq[c], s_sq[tid]);
            }
        }
    }
}

// ============ weight conversion fp32 -> bf16 arena ============
#define W_G1 0
#define W_REL 49152
#define W_ROOT 180224
#define W_G2 311296
#define W_F1 409600
#define W_F2 507904
#define W_TOT 606208

__global__ __launch_bounds__(256) void convert_weights(
    const float* __restrict__ w0, const float* __restrict__ w1, const float* __restrict__ w2,
    const float* __restrict__ w3, const float* __restrict__ w4, const float* __restrict__ w5,
    unsigned short* __restrict__ out)
{
    int i = blockIdx.x * 256 + threadIdx.x;
    if (i >= W_TOT) return;
    const float* src; int off;
    if      (i < W_REL)  { src = w0; off = W_G1; }
    else if (i < W_ROOT) { src = w1; off = W_REL; }
    else if (i < W_G2)   { src = w2; off = W_ROOT; }
    else if (i < W_F1)   { src = w3; off = W_G2; }
    else if (i < W_F2)   { src = w4; off = W_F1; }
    else                 { src = w5; off = W_F2; }
    out[i] = f2bf(src[i - off]);
}

// ============ BN finalize: mu/rs + affine (Av,Bv); self-zeroes sums ============
__global__ __launch_bounds__(256) void bn_finalize(
    float* __restrict__ sum, float* __restrict__ sumsq,
    const float* __restrict__ g, const float* __restrict__ b,
    float* __restrict__ mu, float* __restrict__ rs,
    float* __restrict__ Av, float* __restrict__ Bv, int M, float invN)
{
    int i = blockIdx.x * 256 + threadIdx.x;   // grid 2 -> 512 threads
    if (i < 512) {
        if (i < M) {
            float m = sum[i] * invN;
            float v = sumsq[i] * invN - m * m;
            float r = rsqrtf(v + 1e-5f);
            mu[i] = m; rs[i] = r;
            Av[i] = g[i] * r;
            Bv[i] = b[i] - g[i] * m * r;
        }
        sum[i] = 0.f; sumsq[i] = 0.f;
    }
}

// ============ BN apply (channel-stationary) ============
// MODE: 1 = affine(Av,Bv in g,b slots)+gelu->bf16, 2 = +res(fp32)->bf16, 3 = +res(bf16)->fp32
template <int MODE>
__global__ __launch_bounds__(256) void bn_apply2(
    const unsigned short* __restrict__ pre, const void* __restrict__ resv,
    void* __restrict__ outv, int total8, int M8,
    const float* __restrict__ g, const float* __restrict__ b,
    const float* __restrict__ mu, const float* __restrict__ rs)
{
    const int i0 = blockIdx.x * 256 + threadIdx.x;
    if (i0 >= total8) return;
    const int c = (i0 % M8) * 8;
    float gg[8], bb[8], mm[8], rr[8];
    *(float4*)&gg[0] = *(const float4*)&g[c];   *(float4*)&gg[4] = *(const float4*)&g[c + 4];
    *(float4*)&bb[0] = *(const float4*)&b[c];   *(float4*)&bb[4] = *(const float4*)&b[c + 4];
    if constexpr (MODE != 1) {
        *(float4*)&mm[0] = *(const float4*)&mu[c];  *(float4*)&mm[4] = *(const float4*)&mu[c + 4];
        *(float4*)&rr[0] = *(const float4*)&rs[c];  *(float4*)&rr[4] = *(const float4*)&rs[c + 4];
    }
    const int stride = gridDim.x * 256;
    for (int i = i0; i < total8; i += stride) {
        u16x8 v = *(const u16x8*)&pre[(size_t)i * 8];
        float t[8];
        if constexpr (MODE == 1) {
#pragma unroll
            for (int k = 0; k < 8; ++k) {
                float u = gg[k] * b2f(v[k]) + bb[k];
                t[k] = 0.5f * u * (1.f + erff(u * 0.70710678118654752f));
            }
            unsigned short* ob = (unsigned short*)outv;
            u16x8 o;
#pragma unroll
            for (int k = 0; k < 8; ++k) o[k] = f2bf(t[k]);
            *(u16x8*)&ob[(size_t)i * 8] = o;
        } else {
#pragma unroll
            for (int k = 0; k < 8; ++k)
                t[k] = gg[k] * (b2f(v[k]) - mm[k]) * rr[k] + bb[k];
            if constexpr (MODE == 2) {
                const float* res = (const float*)resv;
                float4 x0 = *(const float4*)&res[(size_t)i * 8];
                float4 x1 = *(const float4*)&res[(size_t)i * 8 + 4];
                t[0] += x0.x; t[1] += x0.y; t[2] += x0.z; t[3] += x0.w;
                t[4] += x1.x; t[5] += x1.y; t[6] += x1.z; t[7] += x1.w;
                unsigned short* ob = (unsigned short*)outv;
                u16x8 o;
#pragma unroll
                for (int k = 0; k < 8; ++k) o[k] = f2bf(t[k]);
                *(u16x8*)&ob[(size_t)i * 8] = o;
            } else {
                const unsigned short* resb = (const unsigned short*)resv;
                u16x8 xb = *(const u16x8*)&resb[(size_t)i * 8];
#pragma unroll
                for (int k = 0; k < 8; ++k) t[k] += b2f(xb[k]);
                float* outp = (float*)outv;
                *(float4*)&outp[(size_t)i * 8]     = make_float4(t[0], t[1], t[2], t[3]);
                *(float4*)&outp[(size_t)i * 8 + 4] = make_float4(t[4], t[5], t[6], t[7]);
            }
        }
    }
}

// ============ CSR build ============
__global__ __launch_bounds__(256) void hist_count(
    const int* __restrict__ dst, int* __restrict__ cnt, int E)
{
    int e = blockIdx.x * blockDim.x + threadIdx.x;
    if (e < E) atomicAdd(&cnt[dst[e]], 1);
}

__global__ __launch_bounds__(256) void scan_block_sums(
    const int* __restrict__ cnt, int* __restrict__ partials, int n)
{
    __shared__ int sdata[256];
    int i = blockIdx.x * 256 + threadIdx.x;
    sdata[threadIdx.x] = (i < n) ? cnt[i] : 0;
    __syncthreads();
    for (int s = 128; s > 0; s >>= 1) {
        if (threadIdx.x < s) sdata[threadIdx.x] += sdata[threadIdx.x + s];
        __syncthreads();
    }
    if (threadIdx.x == 0) partials[blockIdx.x] = sdata[0];
}

__global__ __launch_bounds__(256) void scan_partials(
    int* __restrict__ partials, int nb, int* __restrict__ row_start, int n, int E)
{
    __shared__ int sdata[256];
    const int t = threadIdx.x;
    const int v = (t < nb) ? partials[t] : 0;
    sdata[t] = v;
    __syncthreads();
    for (int s = 1; s < 256; s <<= 1) {
        int u = (t >= s) ? sdata[t - s] : 0;
        __syncthreads();
        sdata[t] += u;
        __syncthreads();
    }
    if (t < nb) partials[t] = sdata[t] - v;
    if (t == 0) row_start[n] = E;
}

__global__ __launch_bounds__(256) void scan_final(
    const int* __restrict__ cnt, const int* __restrict__ partials,
    int* __restrict__ row_start, int n)
{
    __shared__ int sdata[256];
    int i = blockIdx.x * 256 + threadIdx.x;
    int v = (i < n) ? cnt[i] : 0;
    sdata[threadIdx.x] = v;
    __syncthreads();
    for (int s = 1; s < 256; s <<= 1) {
        int t = (threadIdx.x >= s) ? sdata[threadIdx.x - s] : 0;
        __syncthreads();
        sdata[threadIdx.x] += t;
        __syncthreads();
    }
    if (i < n) row_start[i] = partials[blockIdx.x] + sdata[threadIdx.x] - v;
}

__global__ __launch_bounds__(256) void csr_fill(
    const int* __restrict__ src, const int* __restrict__ dst,
    const int* __restrict__ row_start, int* __restrict__ cursor,
    int* __restrict__ srcs_sorted, int E)
{
    int e = blockIdx.x * blockDim.x + threadIdx.x;
    if (e < E) {
        int d = dst[e];
        int pos = row_start[d] + atomicAdd(&cursor[d], 1);
        srcs_sorted[pos] = src[e];
    }
}

// ============ gather-sum with fused BN affine ============
// AGG_bn[n] = Av * (sum of raw Pre rows) + deg * Bv   (exact fold of BN into segsum)
__global__ __launch_bounds__(256) void gather_sum(
    const int* __restrict__ row_start, const int* __restrict__ srcs,
    const unsigned short* __restrict__ T, unsigned short* __restrict__ AGG,
    const float* __restrict__ Av, const float* __restrict__ Bv, int Nn)
{
    int n = blockIdx.x * 4 + (threadIdx.x >> 6);
    if (n >= Nn) return;
    const int lane = threadIdx.x & 63;
    const int half = lane >> 5;
    const int c0 = (lane & 31) * 8;
    const int e0 = row_start[n], e1 = row_start[n + 1];
    float a[8];
#pragma unroll
    for (int k = 0; k < 8; ++k) a[k] = 0.f;

    int e = e0 + half;
    for (; e + 6 < e1; e += 8) {
        int s0 = srcs[e], s1 = srcs[e + 2], s2 = srcs[e + 4], s3 = srcs[e + 6];
        u16x8 v0 = *(const u16x8*)&T[(size_t)s0 * 256 + c0];
        u16x8 v1 = *(const u16x8*)&T[(size_t)s1 * 256 + c0];
        u16x8 v2 = *(const u16x8*)&T[(size_t)s2 * 256 + c0];
        u16x8 v3 = *(const u16x8*)&T[(size_t)s3 * 256 + c0];
#pragma unroll
        for (int k = 0; k < 8; ++k)
            a[k] += (b2f(v0[k]) + b2f(v1[k])) + (b2f(v2[k]) + b2f(v3[k]));
    }
    for (; e < e1; e += 2) {
        int s = srcs[e];
        u16x8 v = *(const u16x8*)&T[(size_t)s * 256 + c0];
#pragma unroll
        for (int k = 0; k < 8; ++k) a[k] += b2f(v[k]);
    }
#pragma unroll
    for (int k = 0; k < 8; ++k) a[k] += __shfl_xor(a[k], 32);
    if (half == 0) {
        const float deg = (float)(e1 - e0);
        float pa[8], pb[8];
        *(float4*)&pa[0] = *(const float4*)&Av[c0];
        *(float4*)&pa[4] = *(const float4*)&Av[c0 + 4];
        *(float4*)&pb[0] = *(const float4*)&Bv[c0];
        *(float4*)&pb[4] = *(const float4*)&Bv[c0 + 4];
        u16x8 o;
#pragma unroll
        for (int k = 0; k < 8; ++k) o[k] = f2bf(pa[k] * a[k] + deg * pb[k]);
        *(u16x8*)&AGG[(size_t)n * 256 + c0] = o;
    }
}

// =====================================================================
extern "C" void kernel_launch(void* const* d_in, const int* in_sizes, int n_in,
                              void* d_out, int out_size, void* d_ws, size_t ws_size,
                              hipStream_t stream)
{
    const float* x        = (const float*)d_in[0];
    const int*   ei       = (const int*)d_in[1];
    const float* w_g1     = (const float*)d_in[2];
    const float* b_g1     = (const float*)d_in[3];
    const float* g1_gamma = (const float*)d_in[4];
    const float* g1_beta  = (const float*)d_in[5];
    const float* w_rel    = (const float*)d_in[6];
    const float* b_rel    = (const float*)d_in[7];
    const float* w_root   = (const float*)d_in[8];
    const float* w_g2     = (const float*)d_in[9];
    const float* b_g2     = (const float*)d_in[10];
    const float* g2_gamma = (const float*)d_in[11];
    const float* g2_beta  = (const float*)d_in[12];
    const float* w_f1     = (const float*)d_in[13];
    const float* b_f1     = (const float*)d_in[14];
    const float* f1_gamma = (const float*)d_in[15];
    const float* f1_beta  = (const float*)d_in[16];
    const float* w_f2     = (const float*)d_in[17];
    const float* b_f2     = (const float*)d_in[18];
    const float* f2_gamma = (const float*)d_in[19];
    const float* f2_beta  = (const float*)d_in[20];

    const int* src = ei;
    const int* dst = ei + EE;

    // workspace layout
    char* p = (char*)d_ws;
    unsigned short* Pre = (unsigned short*)p;   p += (size_t)NN * 512 * 2;  // pre-BN buffers / P12
    unsigned short* R2 = (unsigned short*)p;    p += (size_t)NN * 512 * 2;  // Hb, then Fb
    unsigned short* R3 = (unsigned short*)p;    p += (size_t)NN * 256 * 2;  // CSR scratch, then X2b
    unsigned short* R4 = (unsigned short*)p;    p += (size_t)NN * 256 * 2;  // AGGb
    unsigned short* Wb = (unsigned short*)p;    p += 2 * 1024 * 1024;       // bf16 weights
    float* sum   = (float*)p;
    float* sumsq = sum + 512;
    float* mu    = sum + 1024;
    float* rs    = sum + 1536;
    float* Avec  = sum + 2048;
    float* Bvec  = sum + 2560;

    unsigned short* AGGb = R4;
    unsigned short* Hb   = R2;
    unsigned short* X2b  = R3;
    unsigned short* Fb   = R2;   // gelu output (Hb dead after GEMM step 4)
    unsigned short* P12  = Pre;  // GEMM12 output (Pre dead after gelu pass)

    // CSR scratch in R3 (dead once gather completes; X2b written later)
    int* row_start   = (int*)R3;             // NN+1
    int* cnt         = row_start + NN + 16;
    int* cursor      = cnt + NN;
    int* partials    = cursor + NN;
    int* srcs_sorted = partials + 256;       // EE

    float* out = (float*)d_out;
    const float invN = 1.f / (float)NN;
    dim3 blk(256);
    const int GY = (NN + 127) / 128;         // 391
    const int NB_SCAN = (NN + 255) / 256;    // 196
    const int BN_GRID = 1536;                // 393216 ≡ 0 mod {24,64}

    auto finalize = [&](int M, const float* g, const float* b) {
        hipLaunchKernelGGL(bn_finalize, dim3(2), dim3(256), 0, stream,
                           sum, sumsq, g, b, mu, rs, Avec, Bvec, M, invN);
    };

    // 0. weights -> bf16 arena; zero stats once (finalizes self-zero afterwards)
    hipLaunchKernelGGL(convert_weights, dim3((W_TOT + 255) / 256), blk, 0, stream,
                       w_g1, w_rel, w_root, w_g2, w_f1, w_f2, Wb);
    hipMemsetAsync(sum, 0, 1024 * sizeof(float), stream);

    // ---- Grapher ----
    // 1. Pre = x @ w_g1^T + b_g1   [N,256]  + stats
    hipLaunchKernelGGL((gemm_mfma<1, -1, true>), dim3(2, GY), blk, 0, stream,
                       (const void*)x, Wb + W_G1, nullptr, nullptr, b_g1, nullptr, nullptr,
                       Pre, sum, sumsq, NN, CC, 256);
    finalize(256, g1_gamma, g1_beta);
    // 2. CSR build + gather with fused BN affine (AGGb = Av*segsum(Pre[src]) + deg*Bv)
    hipMemsetAsync(cnt, 0, 2 * NN * sizeof(int), stream);
    hipLaunchKernelGGL(hist_count, dim3((EE + 255) / 256), blk, 0, stream, dst, cnt, EE);
    hipLaunchKernelGGL(scan_block_sums, dim3(NB_SCAN), blk, 0, stream, cnt, partials, NN);
    hipLaunchKernelGGL(scan_partials, dim3(1), dim3(256), 0, stream, partials, NB_SCAN,
                       row_start, NN, EE);
    hipLaunchKernelGGL(scan_final, dim3(NB_SCAN), blk, 0, stream, cnt, partials, row_start, NN);
    hipLaunchKernelGGL(csr_fill, dim3((EE + 255) / 256), blk, 0, stream, src, dst,
                       row_start, cursor, srcs_sorted, EE);
    hipLaunchKernelGGL(gather_sum, dim3((NN + 3) / 4), blk, 0, stream,
                       row_start, srcs_sorted, Pre, AGGb, Avec, Bvec, NN);
    // 3. Hb = bf16(AGGb @ w_rel^T + b_rel + affine(Pre) @ w_root^T)   [N,512]
    hipLaunchKernelGGL((gemm_mfma<0, 2, false>), dim3(4, GY), blk, 0, stream,
                       (const void*)AGGb, Wb + W_REL, (const void*)Pre, Wb + W_ROOT,
                       b_rel, Avec, Bvec, Hb, nullptr, nullptr, NN, 256, 512);
    // 4. Pre = Hb @ w_g2^T + b_g2   [N,192]  + stats
    hipLaunchKernelGGL((gemm_mfma<0, -1, true>), dim3(2, GY), blk, 0, stream,
                       (const void*)Hb, Wb + W_G2, nullptr, nullptr, b_g2, nullptr, nullptr,
                       Pre, sum, sumsq, NN, 512, CC);
    finalize(CC, g2_gamma, g2_beta);
    // 5. X2b = bf16(BN(Pre) + x)
    hipLaunchKernelGGL((bn_apply2<2>), dim3(BN_GRID), blk, 0, stream, Pre, (const void*)x,
                       (void*)X2b, NN * 24, 24, g2_gamma, g2_beta, mu, rs);
    // ---- FFN ----
    // 6. Pre = X2b @ w_f1^T + b_f1   [N,512]  + stats
    hipLaunchKernelGGL((gemm_mfma<0, -1, true>), dim3(4, GY), blk, 0, stream,
                       (const void*)X2b, Wb + W_F1, nullptr, nullptr, b_f1, nullptr, nullptr,
                       Pre, sum, sumsq, NN, CC, 512);
    finalize(512, f1_gamma, f1_beta);
    // 7a. Fb = gelu(affine(Pre))   (standalone channel-stationary pass)
    hipLaunchKernelGGL((bn_apply2<1>), dim3(BN_GRID), blk, 0, stream, Pre, nullptr,
                       (void*)Fb, NN * 64, 64, Avec, Bvec, nullptr, nullptr);
    // 7b. P12 = Fb @ w_f2^T + b_f2   [N,192]  + stats
    hipLaunchKernelGGL((gemm_mfma<0, -1, true>), dim3(2, GY), blk, 0, stream,
                       (const void*)Fb, Wb + W_F2, nullptr, nullptr, b_f2, nullptr, nullptr,
                       P12, sum, sumsq, NN, 512, CC);
    finalize(CC, f2_gamma, f2_beta);
    // 8. out = BN(P12) + X2b
    hipLaunchKernelGGL((bn_apply2<3>), dim3(BN_GRID), blk, 0, stream, P12, (const void*)X2b,
                       (void*)out, NN * 24, 24, f2_gamma, f2_beta, mu, rs);

    (void)in_sizes; (void)n_in; (void)out_size; (void)ws_size;
}

// Round 10
// 398.908 us; speedup vs baseline: 1.1203x; 1.0562x over previous
//
#include <hip/hip_runtime.h>
#include <hip/hip_bf16.h>
#include <math.h>

#define NN 50000
#define EE 800000
#define CC 192

typedef __attribute__((ext_vector_type(4))) float f32x4;
typedef __attribute__((ext_vector_type(8))) short bfx8;
typedef __attribute__((ext_vector_type(8))) unsigned short u16x8;

static __device__ __forceinline__ unsigned short f2bf(float f) {
    return __builtin_bit_cast(unsigned short, __float2bfloat16(f));
}
static __device__ __forceinline__ float b2f(unsigned short u) {
    unsigned v = ((unsigned)u) << 16;
    return __builtin_bit_cast(float, v);
}

// ---- A-staging row converter ----
// MODE: 0 = plain bf16, 1 = fp32->bf16, 2 = affine(A*v+B)->bf16  (no transcendentals here!)
template <int MODE>
static __device__ __forceinline__ bfx8 stage_row(const void* Ap, size_t off, int kc,
                                                 const float* __restrict__ Av,
                                                 const float* __restrict__ Bv)
{
    if constexpr (MODE == 1) {
        const float* A = (const float*)Ap;
        float4 u0 = *(const float4*)&A[off], u1 = *(const float4*)&A[off + 4];
        return bfx8{(short)f2bf(u0.x), (short)f2bf(u0.y), (short)f2bf(u0.z), (short)f2bf(u0.w),
                    (short)f2bf(u1.x), (short)f2bf(u1.y), (short)f2bf(u1.z), (short)f2bf(u1.w)};
    } else {
        u16x8 ra = *(const u16x8*)((const unsigned short*)Ap + off);
        if constexpr (MODE == 0) {
            return __builtin_bit_cast(bfx8, ra);
        } else {
            float pa[8], pb[8];
            *(float4*)&pa[0] = *(const float4*)&Av[kc];
            *(float4*)&pa[4] = *(const float4*)&Av[kc + 4];
            *(float4*)&pb[0] = *(const float4*)&Bv[kc];
            *(float4*)&pb[4] = *(const float4*)&Bv[kc + 4];
            bfx8 o;
#pragma unroll
            for (int j = 0; j < 8; ++j) {
                float t = pa[j] * b2f(ra[j]) + pb[j];
                o[j] = (short)f2bf(t);
            }
            return o;
        }
    }
}

// ============ bf16 MFMA GEMM: out = bf16(f(A1)@W1^T (+ f(A2)@W2^T) + bias) ============
// 128x128 tile, BK=32, 4 waves 2x2, 16x16x32 MFMA, XCD-bijective swizzle,
// fused BN stats, LDS-staged coalesced epilogue. A-modes per stage_row.
// LDS budget exactly 40960 B (stats arrays carved from lds tail) -> 4 blocks/CU.
#define BM 128
#define BKD 32
#define SA 40
#define CT 136

template <int A1M, int A2M, bool STATS>
__global__ __launch_bounds__(256) void gemm_mfma(
    const void* __restrict__ A1v, const unsigned short* __restrict__ W1,
    const void* __restrict__ A2v, const unsigned short* __restrict__ W2,
    const float* __restrict__ bias,
    const float* __restrict__ Av, const float* __restrict__ Bv,
    unsigned short* __restrict__ outb,
    float* __restrict__ gsum, float* __restrict__ gsq,
    int Nrows, int K, int M)
{
    __shared__ short lds[2][2][BM * SA];   // 40960 B; reused as ctile + stats in epilogue
    const int tid  = threadIdx.x;
    const int lane = tid & 63;
    const int wave = tid >> 6;
    const int wm = wave >> 1, wn = wave & 1;

    // bijective XCD swizzle (8 XCDs)
    const int gx = gridDim.x;
    const int nwg = gx * gridDim.y;
    const int linear = blockIdx.y * gx + blockIdx.x;
    const int q = nwg >> 3, r = nwg & 7;
    const int xcd = linear & 7, idx = linear >> 3;
    const int swz = (xcd < r ? xcd * (q + 1) : r * (q + 1) + (xcd - r) * q) + idx;
    const int row0 = (swz / gx) * BM;
    const int col0 = (swz % gx) * BM;

    const int nk = K / BKD;
    const int ntot = (A2M >= 0) ? 2 * nk : nk;

    const int ar = tid >> 2;
    const int ko = (tid & 3) * 8;

    f32x4 acc[4][4];
#pragma unroll
    for (int i = 0; i < 4; ++i)
#pragma unroll
        for (int j = 0; j < 4; ++j) acc[i][j] = f32x4{0.f, 0.f, 0.f, 0.f};

    const int r0c = min(row0 + ar, Nrows - 1);
    const int r1c = min(row0 + ar + 64, Nrows - 1);
    const int c0c = min(col0 + ar, M - 1);
    const int c1c = min(col0 + ar + 64, M - 1);

    auto load_step = [&](int t, bfx8& a0, bfx8& a1, bfx8& b0, bfx8& b1) {
        const int p = (A2M >= 0 && t >= nk) ? 1 : 0;
        const int k0 = (t - p * nk) * BKD;
        const int kc = k0 + ko;
        const unsigned short* W = p ? W2 : W1;
        if (!p) {
            a0 = stage_row<A1M>(A1v, (size_t)r0c * K + kc, kc, Av, Bv);
            a1 = stage_row<A1M>(A1v, (size_t)r1c * K + kc, kc, Av, Bv);
        } else {
            constexpr int M2 = (A2M < 0) ? 0 : A2M;
            a0 = stage_row<M2>(A2v, (size_t)r0c * K + kc, kc, Av, Bv);
            a1 = stage_row<M2>(A2v, (size_t)r1c * K + kc, kc, Av, Bv);
        }
        b0 = *(const bfx8*)&W[(size_t)c0c * K + kc];
        b1 = *(const bfx8*)&W[(size_t)c1c * K + kc];
    };
    auto write_step = [&](int buf, bfx8 a0, bfx8 a1, bfx8 b0, bfx8 b1) {
        *(bfx8*)&lds[buf][0][ar * SA + ko] = a0;
        *(bfx8*)&lds[buf][0][(ar + 64) * SA + ko] = a1;
        *(bfx8*)&lds[buf][1][ar * SA + ko] = b0;
        *(bfx8*)&lds[buf][1][(ar + 64) * SA + ko] = b1;
    };
    auto compute = [&](int buf) {
        const short* Al = lds[buf][0];
        const short* Bl = lds[buf][1];
        bfx8 af[4], bfr[4];
        const int rbase = wm * 64 + (lane & 15);
        const int cbase = wn * 64 + (lane & 15);
        const int kroff = (lane >> 4) * 8;
#pragma unroll
        for (int i = 0; i < 4; ++i) af[i]  = *(const bfx8*)&Al[(rbase + i * 16) * SA + kroff];
#pragma unroll
        for (int j = 0; j < 4; ++j) bfr[j] = *(const bfx8*)&Bl[(cbase + j * 16) * SA + kroff];
#pragma unroll
        for (int i = 0; i < 4; ++i)
#pragma unroll
            for (int j = 0; j < 4; ++j)
                acc[i][j] = __builtin_amdgcn_mfma_f32_16x16x32_bf16(af[i], bfr[j], acc[i][j], 0, 0, 0);
    };

    bfx8 a0, a1, b0, b1;
    load_step(0, a0, a1, b0, b1);
    write_step(0, a0, a1, b0, b1);
    for (int t = 0; t < ntot; ++t) {
        const bool more = (t + 1 < ntot);
        if (more) load_step(t + 1, a0, a1, b0, b1);
        __syncthreads();
        compute(t & 1);
        if (more) write_step((t + 1) & 1, a0, a1, b0, b1);
    }

    // ---- epilogue: LDS-staged coalesced store + register stats ----
    __syncthreads();                                    // all K-loop LDS reads complete
    short* ctile = &lds[0][0][0];                       // [BM][CT] = 34816 B
    float* s_sum = (float*)(&lds[0][0][0] + BM * CT);   // lds tail: 34816..35839
    float* s_sq  = s_sum + BM;
    if (STATS && tid < BM) { s_sum[tid] = 0.f; s_sq[tid] = 0.f; }
    float csA[4], cqA[4];
#pragma unroll
    for (int j = 0; j < 4; ++j) {
        const int cl = wn * 64 + j * 16 + (lane & 15);
        const int c = col0 + cl;
        const float bv = (c < M) ? bias[c] : 0.f;
        float cs = 0.f, cq = 0.f;
#pragma unroll
        for (int i = 0; i < 4; ++i) {
            const int rl = wm * 64 + i * 16 + (lane >> 4) * 4;
#pragma unroll
            for (int r2 = 0; r2 < 4; ++r2) {
                const float val = acc[i][j][r2] + bv;
                ctile[(rl + r2) * CT + cl] = (short)f2bf(val);
                if (STATS) {
                    if (row0 + rl + r2 < Nrows) { cs += val; cq += val * val; }
                }
            }
        }
        if (STATS) {  // pre-reduce across the 4 lanes sharing this column
            cs += __shfl_xor(cs, 16); cs += __shfl_xor(cs, 32);
            cq += __shfl_xor(cq, 16); cq += __shfl_xor(cq, 32);
        }
        csA[j] = cs; cqA[j] = cq;
    }
    __syncthreads();                                    // ctile + stats init visible
    if (STATS && lane < 16) {
#pragma unroll
        for (int j = 0; j < 4; ++j) {
            const int cl = wn * 64 + j * 16 + lane;
            if (col0 + cl < M) {
                atomicAdd(&s_sum[cl], csA[j]);
                atomicAdd(&s_sq[cl], cqA[j]);
            }
        }
    }
    {
        const int rl0 = tid >> 4;
        const int co  = (tid & 15) * 8;
        const int cg  = col0 + co;
        if (cg < M) {
#pragma unroll
            for (int it = 0; it < 8; ++it) {
                const int rl = rl0 + it * 16;
                const int rg = row0 + rl;
                if (rg < Nrows) {
                    u16x8 v = *(const u16x8*)&ctile[rl * CT + co];
                    *(u16x8*)&outb[(size_t)rg * M + cg] = v;
                }
            }
        }
    }
    if (STATS) {
        __syncthreads();                                // LDS atomics drained
        if (tid < BM) {
            const int c = col0 + tid;
            if (c < M) {
                atomicAdd(&gsum[c], s_sum[tid]);
                atomicAdd(&gsq[c], s_sq[tid]);
            }
        }
    }
}

// ============ weight conversion fp32 -> bf16 arena ============
#define W_G1 0
#define W_REL 49152
#define W_ROOT 180224
#define W_G2 311296
#define W_F1 409600
#define W_F2 507904
#define W_TOT 606208

__global__ __launch_bounds__(256) void convert_weights(
    const float* __restrict__ w0, const float* __restrict__ w1, const float* __restrict__ w2,
    const float* __restrict__ w3, const float* __restrict__ w4, const float* __restrict__ w5,
    unsigned short* __restrict__ out)
{
    int i = blockIdx.x * 256 + threadIdx.x;
    if (i >= W_TOT) return;
    const float* src; int off;
    if      (i < W_REL)  { src = w0; off = W_G1; }
    else if (i < W_ROOT) { src = w1; off = W_REL; }
    else if (i < W_G2)   { src = w2; off = W_ROOT; }
    else if (i < W_F1)   { src = w3; off = W_G2; }
    else if (i < W_F2)   { src = w4; off = W_F1; }
    else                 { src = w5; off = W_F2; }
    out[i] = f2bf(src[i - off]);
}

// ============ BN finalize: mu/rs + affine (Av,Bv); self-zeroes sums ============
__global__ __launch_bounds__(256) void bn_finalize(
    float* __restrict__ sum, float* __restrict__ sumsq,
    const float* __restrict__ g, const float* __restrict__ b,
    float* __restrict__ mu, float* __restrict__ rs,
    float* __restrict__ Av, float* __restrict__ Bv, int M, float invN)
{
    int i = blockIdx.x * 256 + threadIdx.x;   // grid 2 -> 512 threads
    if (i < 512) {
        if (i < M) {
            float m = sum[i] * invN;
            float v = sumsq[i] * invN - m * m;
            float r = rsqrtf(v + 1e-5f);
            mu[i] = m; rs[i] = r;
            Av[i] = g[i] * r;
            Bv[i] = b[i] - g[i] * m * r;
        }
        sum[i] = 0.f; sumsq[i] = 0.f;
    }
}

// ============ BN apply (channel-stationary) ============
// MODE: 1 = affine(Av,Bv in g,b slots)+gelu->bf16, 2 = +res(fp32)->bf16, 3 = +res(bf16)->fp32
template <int MODE>
__global__ __launch_bounds__(256) void bn_apply2(
    const unsigned short* __restrict__ pre, const void* __restrict__ resv,
    void* __restrict__ outv, int total8, int M8,
    const float* __restrict__ g, const float* __restrict__ b,
    const float* __restrict__ mu, const float* __restrict__ rs)
{
    const int i0 = blockIdx.x * 256 + threadIdx.x;
    if (i0 >= total8) return;
    const int c = (i0 % M8) * 8;
    float gg[8], bb[8], mm[8], rr[8];
    *(float4*)&gg[0] = *(const float4*)&g[c];   *(float4*)&gg[4] = *(const float4*)&g[c + 4];
    *(float4*)&bb[0] = *(const float4*)&b[c];   *(float4*)&bb[4] = *(const float4*)&b[c + 4];
    if constexpr (MODE != 1) {
        *(float4*)&mm[0] = *(const float4*)&mu[c];  *(float4*)&mm[4] = *(const float4*)&mu[c + 4];
        *(float4*)&rr[0] = *(const float4*)&rs[c];  *(float4*)&rr[4] = *(const float4*)&rs[c + 4];
    }
    const int stride = gridDim.x * 256;
    for (int i = i0; i < total8; i += stride) {
        u16x8 v = *(const u16x8*)&pre[(size_t)i * 8];
        float t[8];
        if constexpr (MODE == 1) {
#pragma unroll
            for (int k = 0; k < 8; ++k) {
                float u = gg[k] * b2f(v[k]) + bb[k];
                t[k] = 0.5f * u * (1.f + erff(u * 0.70710678118654752f));
            }
            unsigned short* ob = (unsigned short*)outv;
            u16x8 o;
#pragma unroll
            for (int k = 0; k < 8; ++k) o[k] = f2bf(t[k]);
            *(u16x8*)&ob[(size_t)i * 8] = o;
        } else {
#pragma unroll
            for (int k = 0; k < 8; ++k)
                t[k] = gg[k] * (b2f(v[k]) - mm[k]) * rr[k] + bb[k];
            if constexpr (MODE == 2) {
                const float* res = (const float*)resv;
                float4 x0 = *(const float4*)&res[(size_t)i * 8];
                float4 x1 = *(const float4*)&res[(size_t)i * 8 + 4];
                t[0] += x0.x; t[1] += x0.y; t[2] += x0.z; t[3] += x0.w;
                t[4] += x1.x; t[5] += x1.y; t[6] += x1.z; t[7] += x1.w;
                unsigned short* ob = (unsigned short*)outv;
                u16x8 o;
#pragma unroll
                for (int k = 0; k < 8; ++k) o[k] = f2bf(t[k]);
                *(u16x8*)&ob[(size_t)i * 8] = o;
            } else {
                const unsigned short* resb = (const unsigned short*)resv;
                u16x8 xb = *(const u16x8*)&resb[(size_t)i * 8];
#pragma unroll
                for (int k = 0; k < 8; ++k) t[k] += b2f(xb[k]);
                float* outp = (float*)outv;
                *(float4*)&outp[(size_t)i * 8]     = make_float4(t[0], t[1], t[2], t[3]);
                *(float4*)&outp[(size_t)i * 8 + 4] = make_float4(t[4], t[5], t[6], t[7]);
            }
        }
    }
}

// ============ CSR build ============
__global__ __launch_bounds__(256) void hist_count(
    const int* __restrict__ dst, int* __restrict__ cnt, int E)
{
    int e = blockIdx.x * blockDim.x + threadIdx.x;
    if (e < E) atomicAdd(&cnt[dst[e]], 1);
}

__global__ __launch_bounds__(256) void scan_block_sums(
    const int* __restrict__ cnt, int* __restrict__ partials, int n)
{
    __shared__ int sdata[256];
    int i = blockIdx.x * 256 + threadIdx.x;
    sdata[threadIdx.x] = (i < n) ? cnt[i] : 0;
    __syncthreads();
    for (int s = 128; s > 0; s >>= 1) {
        if (threadIdx.x < s) sdata[threadIdx.x] += sdata[threadIdx.x + s];
        __syncthreads();
    }
    if (threadIdx.x == 0) partials[blockIdx.x] = sdata[0];
}

__global__ __launch_bounds__(256) void scan_partials(
    int* __restrict__ partials, int nb, int* __restrict__ row_start, int n, int E)
{
    __shared__ int sdata[256];
    const int t = threadIdx.x;
    const int v = (t < nb) ? partials[t] : 0;
    sdata[t] = v;
    __syncthreads();
    for (int s = 1; s < 256; s <<= 1) {
        int u = (t >= s) ? sdata[t - s] : 0;
        __syncthreads();
        sdata[t] += u;
        __syncthreads();
    }
    if (t < nb) partials[t] = sdata[t] - v;
    if (t == 0) row_start[n] = E;
}

__global__ __launch_bounds__(256) void scan_final(
    const int* __restrict__ cnt, const int* __restrict__ partials,
    int* __restrict__ row_start, int n)
{
    __shared__ int sdata[256];
    int i = blockIdx.x * 256 + threadIdx.x;
    int v = (i < n) ? cnt[i] : 0;
    sdata[threadIdx.x] = v;
    __syncthreads();
    for (int s = 1; s < 256; s <<= 1) {
        int t = (threadIdx.x >= s) ? sdata[threadIdx.x - s] : 0;
        __syncthreads();
        sdata[threadIdx.x] += t;
        __syncthreads();
    }
    if (i < n) row_start[i] = partials[blockIdx.x] + sdata[threadIdx.x] - v;
}

__global__ __launch_bounds__(256) void csr_fill(
    const int* __restrict__ src, const int* __restrict__ dst,
    const int* __restrict__ row_start, int* __restrict__ cursor,
    int* __restrict__ srcs_sorted, int E)
{
    int e = blockIdx.x * blockDim.x + threadIdx.x;
    if (e < E) {
        int d = dst[e];
        int pos = row_start[d] + atomicAdd(&cursor[d], 1);
        srcs_sorted[pos] = src[e];
    }
}

// ============ gather-sum with fused BN affine ============
// AGG_bn[n] = Av * (sum of raw Pre rows) + deg * Bv   (exact fold of BN into segsum)
__global__ __launch_bounds__(256) void gather_sum(
    const int* __restrict__ row_start, const int* __restrict__ srcs,
    const unsigned short* __restrict__ T, unsigned short* __restrict__ AGG,
    const float* __restrict__ Av, const float* __restrict__ Bv, int Nn)
{
    int n = blockIdx.x * 4 + (threadIdx.x >> 6);
    if (n >= Nn) return;
    const int lane = threadIdx.x & 63;
    const int half = lane >> 5;
    const int c0 = (lane & 31) * 8;
    const int e0 = row_start[n], e1 = row_start[n + 1];
    float a[8];
#pragma unroll
    for (int k = 0; k < 8; ++k) a[k] = 0.f;

    int e = e0 + half;
    for (; e + 6 < e1; e += 8) {
        int s0 = srcs[e], s1 = srcs[e + 2], s2 = srcs[e + 4], s3 = srcs[e + 6];
        u16x8 v0 = *(const u16x8*)&T[(size_t)s0 * 256 + c0];
        u16x8 v1 = *(const u16x8*)&T[(size_t)s1 * 256 + c0];
        u16x8 v2 = *(const u16x8*)&T[(size_t)s2 * 256 + c0];
        u16x8 v3 = *(const u16x8*)&T[(size_t)s3 * 256 + c0];
#pragma unroll
        for (int k = 0; k < 8; ++k)
            a[k] += (b2f(v0[k]) + b2f(v1[k])) + (b2f(v2[k]) + b2f(v3[k]));
    }
    for (; e < e1; e += 2) {
        int s = srcs[e];
        u16x8 v = *(const u16x8*)&T[(size_t)s * 256 + c0];
#pragma unroll
        for (int k = 0; k < 8; ++k) a[k] += b2f(v[k]);
    }
#pragma unroll
    for (int k = 0; k < 8; ++k) a[k] += __shfl_xor(a[k], 32);
    if (half == 0) {
        const float deg = (float)(e1 - e0);
        float pa[8], pb[8];
        *(float4*)&pa[0] = *(const float4*)&Av[c0];
        *(float4*)&pa[4] = *(const float4*)&Av[c0 + 4];
        *(float4*)&pb[0] = *(const float4*)&Bv[c0];
        *(float4*)&pb[4] = *(const float4*)&Bv[c0 + 4];
        u16x8 o;
#pragma unroll
        for (int k = 0; k < 8; ++k) o[k] = f2bf(pa[k] * a[k] + deg * pb[k]);
        *(u16x8*)&AGG[(size_t)n * 256 + c0] = o;
    }
}

// =====================================================================
extern "C" void kernel_launch(void* const* d_in, const int* in_sizes, int n_in,
                              void* d_out, int out_size, void* d_ws, size_t ws_size,
                              hipStream_t stream)
{
    const float* x        = (const float*)d_in[0];
    const int*   ei       = (const int*)d_in[1];
    const float* w_g1     = (const float*)d_in[2];
    const float* b_g1     = (const float*)d_in[3];
    const float* g1_gamma = (const float*)d_in[4];
    const float* g1_beta  = (const float*)d_in[5];
    const float* w_rel    = (const float*)d_in[6];
    const float* b_rel    = (const float*)d_in[7];
    const float* w_root   = (const float*)d_in[8];
    const float* w_g2     = (const float*)d_in[9];
    const float* b_g2     = (const float*)d_in[10];
    const float* g2_gamma = (const float*)d_in[11];
    const float* g2_beta  = (const float*)d_in[12];
    const float* w_f1     = (const float*)d_in[13];
    const float* b_f1     = (const float*)d_in[14];
    const float* f1_gamma = (const float*)d_in[15];
    const float* f1_beta  = (const float*)d_in[16];
    const float* w_f2     = (const float*)d_in[17];
    const float* b_f2     = (const float*)d_in[18];
    const float* f2_gamma = (const float*)d_in[19];
    const float* f2_beta  = (const float*)d_in[20];

    const int* src = ei;
    const int* dst = ei + EE;

    // workspace layout
    char* p = (char*)d_ws;
    unsigned short* Pre = (unsigned short*)p;   p += (size_t)NN * 512 * 2;  // pre-BN buffers / P12
    unsigned short* R2 = (unsigned short*)p;    p += (size_t)NN * 512 * 2;  // Hb, then Fb
    unsigned short* R3 = (unsigned short*)p;    p += (size_t)NN * 256 * 2;  // CSR scratch, then X2b
    unsigned short* R4 = (unsigned short*)p;    p += (size_t)NN * 256 * 2;  // AGGb
    unsigned short* Wb = (unsigned short*)p;    p += 2 * 1024 * 1024;       // bf16 weights
    float* sum   = (float*)p;
    float* sumsq = sum + 512;
    float* mu    = sum + 1024;
    float* rs    = sum + 1536;
    float* Avec  = sum + 2048;
    float* Bvec  = sum + 2560;

    unsigned short* AGGb = R4;
    unsigned short* Hb   = R2;
    unsigned short* X2b  = R3;
    unsigned short* Fb   = R2;   // gelu output (Hb dead after GEMM step 4)
    unsigned short* P12  = Pre;  // GEMM12 output (Pre dead after gelu pass)

    // CSR scratch in R3 (dead once gather completes; X2b written later)
    int* row_start   = (int*)R3;             // NN+1
    int* cnt         = row_start + NN + 16;
    int* cursor      = cnt + NN;
    int* partials    = cursor + NN;
    int* srcs_sorted = partials + 256;       // EE

    float* out = (float*)d_out;
    const float invN = 1.f / (float)NN;
    dim3 blk(256);
    const int GY = (NN + 127) / 128;         // 391
    const int NB_SCAN = (NN + 255) / 256;    // 196
    const int BN_GRID = 1536;                // 393216 ≡ 0 mod {24,64}

    auto finalize = [&](int M, const float* g, const float* b) {
        hipLaunchKernelGGL(bn_finalize, dim3(2), dim3(256), 0, stream,
                           sum, sumsq, g, b, mu, rs, Avec, Bvec, M, invN);
    };

    // 0. weights -> bf16 arena; zero stats once (finalizes self-zero afterwards)
    hipLaunchKernelGGL(convert_weights, dim3((W_TOT + 255) / 256), blk, 0, stream,
                       w_g1, w_rel, w_root, w_g2, w_f1, w_f2, Wb);
    hipMemsetAsync(sum, 0, 1024 * sizeof(float), stream);

    // ---- Grapher ----
    // 1. Pre = x @ w_g1^T + b_g1   [N,256]  + stats
    hipLaunchKernelGGL((gemm_mfma<1, -1, true>), dim3(2, GY), blk, 0, stream,
                       (const void*)x, Wb + W_G1, nullptr, nullptr, b_g1, nullptr, nullptr,
                       Pre, sum, sumsq, NN, CC, 256);
    finalize(256, g1_gamma, g1_beta);
    // 2. CSR build + gather with fused BN affine (AGGb = Av*segsum(Pre[src]) + deg*Bv)
    hipMemsetAsync(cnt, 0, 2 * NN * sizeof(int), stream);
    hipLaunchKernelGGL(hist_count, dim3((EE + 255) / 256), blk, 0, stream, dst, cnt, EE);
    hipLaunchKernelGGL(scan_block_sums, dim3(NB_SCAN), blk, 0, stream, cnt, partials, NN);
    hipLaunchKernelGGL(scan_partials, dim3(1), dim3(256), 0, stream, partials, NB_SCAN,
                       row_start, NN, EE);
    hipLaunchKernelGGL(scan_final, dim3(NB_SCAN), blk, 0, stream, cnt, partials, row_start, NN);
    hipLaunchKernelGGL(csr_fill, dim3((EE + 255) / 256), blk, 0, stream, src, dst,
                       row_start, cursor, srcs_sorted, EE);
    hipLaunchKernelGGL(gather_sum, dim3((NN + 3) / 4), blk, 0, stream,
                       row_start, srcs_sorted, Pre, AGGb, Avec, Bvec, NN);
    // 3. Hb = bf16(AGGb @ w_rel^T + b_rel + affine(Pre) @ w_root^T)   [N,512]
    hipLaunchKernelGGL((gemm_mfma<0, 2, false>), dim3(4, GY), blk, 0, stream,
                       (const void*)AGGb, Wb + W_REL, (const void*)Pre, Wb + W_ROOT,
                       b_rel, Avec, Bvec, Hb, nullptr, nullptr, NN, 256, 512);
    // 4. Pre = Hb @ w_g2^T + b_g2   [N,192]  + stats
    hipLaunchKernelGGL((gemm_mfma<0, -1, true>), dim3(2, GY), blk, 0, stream,
                       (const void*)Hb, Wb + W_G2, nullptr, nullptr, b_g2, nullptr, nullptr,
                       Pre, sum, sumsq, NN, 512, CC);
    finalize(CC, g2_gamma, g2_beta);
    // 5. X2b = bf16(BN(Pre) + x)
    hipLaunchKernelGGL((bn_apply2<2>), dim3(BN_GRID), blk, 0, stream, Pre, (const void*)x,
                       (void*)X2b, NN * 24, 24, g2_gamma, g2_beta, mu, rs);
    // ---- FFN ----
    // 6. Pre = X2b @ w_f1^T + b_f1   [N,512]  + stats
    hipLaunchKernelGGL((gemm_mfma<0, -1, true>), dim3(4, GY), blk, 0, stream,
                       (const void*)X2b, Wb + W_F1, nullptr, nullptr, b_f1, nullptr, nullptr,
                       Pre, sum, sumsq, NN, CC, 512);
    finalize(512, f1_gamma, f1_beta);
    // 7a. Fb = gelu(affine(Pre))   (standalone channel-stationary pass)
    hipLaunchKernelGGL((bn_apply2<1>), dim3(BN_GRID), blk, 0, stream, Pre, nullptr,
                       (void*)Fb, NN * 64, 64, Avec, Bvec, nullptr, nullptr);
    // 7b. P12 = Fb @ w_f2^T + b_f2   [N,192]  + stats
    hipLaunchKernelGGL((gemm_mfma<0, -1, true>), dim3(2, GY), blk, 0, stream,
                       (const void*)Fb, Wb + W_F2, nullptr, nullptr, b_f2, nullptr, nullptr,
                       P12, sum, sumsq, NN, 512, CC);
    finalize(CC, f2_gamma, f2_beta);
    // 8. out = BN(P12) + X2b
    hipLaunchKernelGGL((bn_apply2<3>), dim3(BN_GRID), blk, 0, stream, P12, (const void*)X2b,
                       (void*)out, NN * 24, 24, f2_gamma, f2_beta, mu, rs);

    (void)in_sizes; (void)n_in; (void)out_size; (void)ws_size;
}